// Round 3
// baseline (11196.313 us; speedup 1.0000x reference)
//
#include <hip/hip_runtime.h>
#include <cstdint>
#include <cstddef>

#define SEQ   512
#define BATCH 64
#define DIN   256
#define HDIM  1024
#define NGROUP 8      // batch groups (g = blk & 7)
#define GROWS  8      // rows per group
#define NSLAB  32     // column slabs per group (j = blk >> 3)

typedef __attribute__((ext_vector_type(8)))  short  short8;
typedef __attribute__((ext_vector_type(4)))  short  short4v;
typedef __attribute__((ext_vector_type(4)))  float  float4v;

__device__ __forceinline__ short f2bf(float f) {
    union { float f; uint32_t u; } v; v.f = f;
    uint32_t u = v.u;
    uint32_t r = (u + 0x7fffu + ((u >> 16) & 1u)) >> 16;
    return (short)(r & 0xffffu);
}
__device__ __forceinline__ float bf2f(short s) {
    union { uint32_t u; float f; } v; v.u = ((uint32_t)(uint16_t)s) << 16;
    return v.f;
}
__device__ __forceinline__ float fast_tanh(float x) {
    float ax = __builtin_fabsf(x);
    float e  = __builtin_amdgcn_exp2f(ax * -2.885390081777927f); // exp2(-2*log2e*|x|)
    float r  = (1.0f - e) * __builtin_amdgcn_rcpf(1.0f + e);
    return x < 0.0f ? -r : r;
}

// ---------------------------------------------------------------------------
// prep: W_hh -> bf16 hi/lo planes; zero h buffer 0 (both planes); zero prog
// ---------------------------------------------------------------------------
__global__ void prep_kernel(const float* __restrict__ W_hh,
                            short* __restrict__ w_hi,
                            short* __restrict__ w_lo,
                            short* __restrict__ hbuf,
                            unsigned int* __restrict__ prog) {
    int tid = blockIdx.x * blockDim.x + threadIdx.x;
    int stride = gridDim.x * blockDim.x;
    for (int i = tid; i < HDIM * HDIM; i += stride) {
        float w = W_hh[i];
        short hi = f2bf(w);
        float lo = w - bf2f(hi);
        w_hi[i] = hi;
        w_lo[i] = f2bf(lo);
    }
    for (int i = tid; i < 2 * BATCH * HDIM; i += stride) hbuf[i] = 0;
    for (int i = tid; i < NGROUP * NSLAB; i += stride) prog[i] = 0u;
}

// ---------------------------------------------------------------------------
// xproj: out[r][j] = sum_i X[r][i] * Win[j][i] + bias[j]   (unchanged)
// ---------------------------------------------------------------------------
#define XBM 128
#define XBN 128
#define XBK 32

__global__ __launch_bounds__(256) void xproj_kernel(
    const float* __restrict__ X,
    const float* __restrict__ Win,
    const float* __restrict__ bias,
    float* __restrict__ out)
{
    __shared__ float As[XBK][XBM + 4];
    __shared__ float Bs[XBK][XBN + 4];
    const int bm = blockIdx.x;
    const int bn = blockIdx.y;
    const int r0 = bm * XBM, c0 = bn * XBN;
    const int tid = threadIdx.x;
    const int tx = tid & 15, ty = tid >> 4;

    float acc[8][8];
#pragma unroll
    for (int i = 0; i < 8; i++)
#pragma unroll
        for (int j = 0; j < 8; j++) acc[i][j] = 0.f;

    for (int k0 = 0; k0 < DIN; k0 += XBK) {
#pragma unroll
        for (int r = 0; r < 4; r++) {
            int row = (tid >> 3) + 32 * r;
            int kk  = (tid & 7) * 4;
            float4v v = *(const float4v*)(X + (size_t)(r0 + row) * DIN + k0 + kk);
            As[kk + 0][row] = v[0]; As[kk + 1][row] = v[1];
            As[kk + 2][row] = v[2]; As[kk + 3][row] = v[3];
        }
#pragma unroll
        for (int r = 0; r < 4; r++) {
            int row = (tid >> 3) + 32 * r;
            int kk  = (tid & 7) * 4;
            float4v v = *(const float4v*)(Win + (size_t)(c0 + row) * DIN + k0 + kk);
            Bs[kk + 0][row] = v[0]; Bs[kk + 1][row] = v[1];
            Bs[kk + 2][row] = v[2]; Bs[kk + 3][row] = v[3];
        }
        __syncthreads();
#pragma unroll
        for (int k = 0; k < XBK; k++) {
            float4v a0 = *(const float4v*)&As[k][ty * 8];
            float4v a1 = *(const float4v*)&As[k][ty * 8 + 4];
            float4v b0 = *(const float4v*)&Bs[k][tx * 8];
            float4v b1 = *(const float4v*)&Bs[k][tx * 8 + 4];
            float a[8] = {a0[0],a0[1],a0[2],a0[3],a1[0],a1[1],a1[2],a1[3]};
            float b[8] = {b0[0],b0[1],b0[2],b0[3],b1[0],b1[1],b1[2],b1[3]};
#pragma unroll
            for (int i = 0; i < 8; i++)
#pragma unroll
                for (int j = 0; j < 8; j++) acc[i][j] += a[i] * b[j];
        }
        __syncthreads();
    }

    float4v ba = *(const float4v*)(bias + c0 + tx * 8);
    float4v bb = *(const float4v*)(bias + c0 + tx * 8 + 4);
#pragma unroll
    for (int i = 0; i < 8; i++) {
        size_t row = (size_t)(r0 + ty * 8 + i);
        float4v v0, v1;
#pragma unroll
        for (int j = 0; j < 4; j++) { v0[j] = acc[i][j] + ba[j]; v1[j] = acc[i][4 + j] + bb[j]; }
        *(float4v*)(out + row * HDIM + c0 + tx * 8)     = v0;
        *(float4v*)(out + row * HDIM + c0 + tx * 8 + 4) = v1;
    }
}

// ---------------------------------------------------------------------------
// rnn3: 256 blocks x 512 threads. Block (g=blk&7, j=blk>>3).
// Per-wave source flags, fence+plain-load exchange, W pinned in VGPRs,
// single syncthreads/step with double-buffered zbuf, 1-wave epilogue,
// xp prefetch after publish.
// ---------------------------------------------------------------------------
__global__ __launch_bounds__(512, 2) void rnn3_kernel(
    const float* __restrict__ alpha,
    const short* __restrict__ w_hi,
    const short* __restrict__ w_lo,
    short* __restrict__ hbuf,          // [2 buf][2 plane][BATCH][HDIM]
    unsigned int* __restrict__ prog,   // [NSLAB*NGROUP], idx = j*8+g
    float* __restrict__ out)           // [SEQ][BATCH][HDIM] then h_n
{
    __shared__ float zbuf[2][8][2][16][20];   // [buf][kq][nt][m][n(pad 20)]

    const int blk  = blockIdx.x;
    const int g    = blk & 7;
    const int j    = blk >> 3;
    const int tid  = threadIdx.x;
    const int kq   = tid >> 6;          // wave = k-slice of 128
    const int lane = tid & 63;
    const int ln15 = lane & 15;
    const int kg   = lane >> 4;
    const int k_base = kq * 128 + kg * 8;
    const bool mvalid = (ln15 < GROWS);
    const int arow = g * GROWS + ln15;

    // --- W fragments, resident across all steps ---
    short8 wf[2][4][2];
#pragma unroll
    for (int nt = 0; nt < 2; nt++)
#pragma unroll
        for (int kt = 0; kt < 4; kt++) {
            int col = j * 32 + nt * 16 + ln15;
            int k   = k_base + kt * 32;
            wf[nt][kt][0] = *(const short8*)(w_hi + (size_t)col * HDIM + k);
            wf[nt][kt][1] = *(const short8*)(w_lo + (size_t)col * HDIM + k);
        }

    // --- epilogue state (wave 0 only): 8 rows x 32 cols, 4 cols/thread ---
    const int em   = tid >> 3;          // 0..7 (row)
    const int c04  = (tid & 7) * 4;     // 0..28 (col within slab)
    const int erow = g * GROWS + em;
    const int egc  = j * 32 + c04;
    const int ent  = c04 >> 4, en0 = c04 & 15;
    float4v al = {0.f,0.f,0.f,0.f}, xpv = {0.f,0.f,0.f,0.f};
    float4v hp = {0.f,0.f,0.f,0.f};
    if (tid < 64) {
        al  = *(const float4v*)(alpha + egc);
        xpv = *(const float4v*)(out + (size_t)erow * HDIM + egc);   // xp(t=0)
    }

    for (int t = 0; t < SEQ; t++) {
        const int buf = t & 1;
        const short* hhi = hbuf + (size_t)(buf * 2 + 0) * BATCH * HDIM;
        const short* hlo = hbuf + (size_t)(buf * 2 + 1) * BATCH * HDIM;

        // pin W fragments in VGPRs (defeat rematerialization/spill)
#pragma unroll
        for (int nt = 0; nt < 2; nt++)
#pragma unroll
            for (int kt = 0; kt < 4; kt++) {
                asm volatile("" : "+v"(wf[nt][kt][0]));
                asm volatile("" : "+v"(wf[nt][kt][1]));
            }

        if (t > 0) {
            // wave kq needs slabs 4kq..4kq+3 of group g at step >= t
            const unsigned int* fp = prog + ((4 * kq + (lane & 3)) * NGROUP + g);
            const bool active = (lane < 4);
            unsigned v = active ? __hip_atomic_load(fp, __ATOMIC_RELAXED,
                                                    __HIP_MEMORY_SCOPE_AGENT)
                                : 0xFFFFFFFFu;
            while (__any(v < (unsigned)t)) {
                v = active ? __hip_atomic_load(fp, __ATOMIC_RELAXED,
                                               __HIP_MEMORY_SCOPE_AGENT)
                           : 0xFFFFFFFFu;
            }
            __builtin_amdgcn_fence(__ATOMIC_ACQUIRE, "agent");
        }

        // --- A-fragment loads (plain, batch-issued, fresh after fence) ---
        short8 ahi[4], alo[4];
#pragma unroll
        for (int kt = 0; kt < 4; kt++) {
            if (mvalid) {
                ahi[kt] = *(const short8*)(hhi + (size_t)arow * HDIM + k_base + kt * 32);
                alo[kt] = *(const short8*)(hlo + (size_t)arow * HDIM + k_base + kt * 32);
            } else {
                ahi[kt] = (short8)0; alo[kt] = (short8)0;
            }
        }

        float4v acc0 = {0.f,0.f,0.f,0.f}, acc1 = {0.f,0.f,0.f,0.f};
#pragma unroll
        for (int kt = 0; kt < 4; kt++) {
            acc0 = __builtin_amdgcn_mfma_f32_16x16x32_bf16(ahi[kt], wf[0][kt][0], acc0, 0, 0, 0);
            acc1 = __builtin_amdgcn_mfma_f32_16x16x32_bf16(ahi[kt], wf[1][kt][0], acc1, 0, 0, 0);
            acc0 = __builtin_amdgcn_mfma_f32_16x16x32_bf16(ahi[kt], wf[0][kt][1], acc0, 0, 0, 0);
            acc1 = __builtin_amdgcn_mfma_f32_16x16x32_bf16(ahi[kt], wf[1][kt][1], acc1, 0, 0, 0);
            acc0 = __builtin_amdgcn_mfma_f32_16x16x32_bf16(alo[kt], wf[0][kt][0], acc0, 0, 0, 0);
            acc1 = __builtin_amdgcn_mfma_f32_16x16x32_bf16(alo[kt], wf[1][kt][0], acc1, 0, 0, 0);
        }
        // C/D: col = lane&15, row = kg*4 + reg
#pragma unroll
        for (int reg = 0; reg < 4; reg++) {
            int m = kg * 4 + reg;
            zbuf[buf][kq][0][m][ln15] = acc0[reg];
            zbuf[buf][kq][1][m][ln15] = acc1[reg];
        }
        __syncthreads();

        // --- epilogue: wave 0 only ---
        if (tid < 64) {
            float4v z = xpv;
#pragma unroll
            for (int q = 0; q < 8; q++) {
                float4v zz = *(const float4v*)&zbuf[buf][q][ent][em][en0];
                z += zz;
            }
            float4v res;
#pragma unroll
            for (int c = 0; c < 4; c++) {
                float ht = fast_tanh(z[c]);
                hp[c] = (1.0f - al[c]) * hp[c] + al[c] * ht;
                res[c] = hp[c];
            }
            size_t oidx = (size_t)t * (BATCH * HDIM) + (size_t)erow * HDIM + egc;
            __builtin_nontemporal_store(res, (float4v*)(out + oidx));
            if (t == SEQ - 1) {
                *(float4v*)(out + (size_t)SEQ * BATCH * HDIM + (size_t)erow * HDIM + egc) = res;
            } else {
                short4v nhi, nlo;
#pragma unroll
                for (int c = 0; c < 4; c++) {
                    short hi = f2bf(hp[c]);
                    nhi[c] = hi;
                    nlo[c] = f2bf(hp[c] - bf2f(hi));
                }
                const int nb = buf ^ 1;
                union { short4v s; unsigned long long u; } uh, ul;
                uh.s = nhi; ul.s = nlo;
                unsigned long long* dhi = (unsigned long long*)
                    (hbuf + ((size_t)(nb * 2 + 0) * BATCH + erow) * HDIM + egc);
                unsigned long long* dlo = (unsigned long long*)
                    (hbuf + ((size_t)(nb * 2 + 1) * BATCH + erow) * HDIM + egc);
                __hip_atomic_store(dhi, uh.u, __ATOMIC_RELAXED, __HIP_MEMORY_SCOPE_AGENT);
                __hip_atomic_store(dlo, ul.u, __ATOMIC_RELAXED, __HIP_MEMORY_SCOPE_AGENT);
                if (tid == 0) {
                    // release: drains the wave's h stores, then publishes
                    __hip_atomic_store(&prog[blk], (unsigned)(t + 1),
                                       __ATOMIC_RELEASE, __HIP_MEMORY_SCOPE_AGENT);
                }
                // prefetch xp(t+1); HBM latency hides under next poll
                xpv = *(const float4v*)(out + (size_t)(t + 1) * (BATCH * HDIM)
                                        + (size_t)erow * HDIM + egc);
            }
        }
    }
}

// ---------------------------------------------------------------------------
extern "C" void kernel_launch(void* const* d_in, const int* in_sizes, int n_in,
                              void* d_out, int out_size, void* d_ws, size_t ws_size,
                              hipStream_t stream) {
    const float* x     = (const float*)d_in[0];
    const float* W_in  = (const float*)d_in[1];
    const float* W_hh  = (const float*)d_in[2];
    const float* bias  = (const float*)d_in[3];
    const float* alpha = (const float*)d_in[4];
    float* out = (float*)d_out;

    short* w_hi = (short*)d_ws;                               // 2 MB
    short* w_lo = w_hi + (size_t)HDIM * HDIM;                 // 2 MB
    short* hbuf = w_lo + (size_t)HDIM * HDIM;                 // 512 KB
    unsigned int* prog = (unsigned int*)(hbuf + (size_t)2 * 2 * BATCH * HDIM);

    prep_kernel<<<512, 256, 0, stream>>>(W_hh, w_hi, w_lo, hbuf, prog);

    dim3 xg(SEQ * BATCH / XBM, HDIM / XBN);
    xproj_kernel<<<xg, 256, 0, stream>>>(x, W_in, bias, out);

    void* args[] = { (void*)&alpha, (void*)&w_hi, (void*)&w_lo,
                     (void*)&hbuf, (void*)&prog, (void*)&out };
    (void)hipLaunchCooperativeKernel((const void*)rnn3_kernel,
                                     dim3(NGROUP * NSLAB), dim3(512),
                                     args, 0, stream);
}